// Round 7
// baseline (606.299 us; speedup 1.0000x reference)
//
#include <hip/hip_runtime.h>
#include <math.h>

#define M_LEN 40000
#define B_SZ 16
#define K_TAPS 201
#define T_HALF 100
#define L_OUT 39800          // M_LEN - K_TAPS + 1
#define TL 256               // outputs per block
#define NTILES 156           // ceil(L_OUT / TL)
#define NP 456               // TL + K_TAPS - 1
#define NPS 458              // NP + 2 : staged series positions
#define NPX 460              // NP + 4 : x positions
#define XSTR 464             // x f16 stride
#define PAIRS 240            // staged series pairs (max read index 231)
#define SSTR 242             // series pair-array stride in dwords (even!)
#define NSER 20
#define WPP 104              // weight pairs per array (208 taps)
#define NWARR 28             // 4 base + 2 sg x 12

typedef unsigned int uint;
typedef __fp16 h2 __attribute__((ext_vector_type(2)));

static __device__ __forceinline__ h2 U2H(uint u){ h2 r; __builtin_memcpy(&r,&u,4); return r; }
static __device__ __forceinline__ uint H2U(h2 h){ uint r; __builtin_memcpy(&r,&h,4); return r; }

#define FDOT2(w,v,acc) (acc) = __builtin_amdgcn_fdot2((w),(v),(acc),false)

// ---------------- prep kernel -------------------------------------------------
// Global weight array layout (each WPP uints): 0 wx_v0, 1 wx_v1, 2 wc_v0, 3 wc_v1,
// then per sg block at 4+sg*12: kind pairs (v0,v1) for
// kind 0 wPr, 1 wPi, 2 wNr, 3 wNi, 4 nWpi(=-wPi), 5 nWnr(=-wNr)
// version 0: pair p = (w[2p], w[2p+1]); version 1: (w[2p-1], w[2p])
static __device__ float wkind(int kind, int sg, int t,
                              const float* wr, const float* wi) {
    if (kind == 0) return (t >= 0 && t <= 200) ? wr[(2 + sg) * K_TAPS + t] : 0.f;
    if (kind == 1) return (t >= 0 && t <= 200) ? wi[(2 + sg) * K_TAPS + t] : 0.f;
    int tt = t - (sg + 1);
    if (kind == 2) return (tt >= 0 && tt <= 200) ? wr[(1 - sg) * K_TAPS + tt] : 0.f;
    if (kind == 3) return (tt >= 0 && tt <= 200) ? wi[(1 - sg) * K_TAPS + tt] : 0.f;
    if (kind == 4) return -wkind(1, sg, t, wr, wi);
    return -wkind(2, sg, t, wr, wi);
}

__global__ void prep_weights(const float* __restrict__ wx, const float* __restrict__ wc,
                             const float* __restrict__ wr, const float* __restrict__ wi,
                             uint* __restrict__ W) {
    int idx = blockIdx.x * 256 + threadIdx.x;
    if (idx >= NWARR * WPP) return;
    int p = idx % WPP;
    int a = idx / WPP;
    float f0, f1;
    if (a < 4) {
        int ver = a & 1;
        const float* src = (a < 2) ? wx : wc;
        int t0 = 2 * p - ver;
        f0 = (t0     >= 0 && t0     <= 200) ? src[t0]     : 0.f;
        f1 = (t0 + 1 >= 0 && t0 + 1 <= 200) ? src[t0 + 1] : 0.f;
    } else {
        int q = a - 4;
        int sg = q / 12, r = q % 12;
        int kind = r >> 1, ver = r & 1;
        int t0 = 2 * p - ver;
        f0 = wkind(kind, sg, t0,     wr, wi);
        f1 = wkind(kind, sg, t0 + 1, wr, wi);
    }
    W[idx] = H2U(__builtin_amdgcn_cvt_pkrtz(f0, f1));
}

// ---------------- conv passes (series-major) ----------------------------------
// Window for tap-block k covers pairs [8k .. 8k+9] relative to thread base.
// hp[t] (t=0..9) = pair (base_pos + 2(8k+t)).  Outputs o: even use v0 weights,
// odd use v1 (shifted) weights; o>=2 use hp[.+1].

// 1 weight vector (v0 at W0, v1 at W0+WPP) -> 4 accs. 32 fdot2 / k.
static __device__ __forceinline__ void pass1(const uint* base, const uint* __restrict__ W0,
                                             float* acc) {
    const uint* W1 = W0 + WPP;
    uint2 c  = *(const uint2*)(base);
    uint2 u1 = *(const uint2*)(base + 2);
    uint2 u2 = *(const uint2*)(base + 4);
    uint2 u3 = *(const uint2*)(base + 6);
    uint2 u4 = *(const uint2*)(base + 8);
#pragma unroll 1
    for (int k = 0; k < 13; ++k) {
        const int ko = 8 * k;
        uint2 n1, n2, n3, n4;
        if (k < 12) {
            n1 = *(const uint2*)(base + ko + 10);
            n2 = *(const uint2*)(base + ko + 12);
            n3 = *(const uint2*)(base + ko + 14);
            n4 = *(const uint2*)(base + ko + 16);
        }
        h2 hp[10] = {U2H(c.x),  U2H(c.y),  U2H(u1.x), U2H(u1.y), U2H(u2.x),
                     U2H(u2.y), U2H(u3.x), U2H(u3.y), U2H(u4.x), U2H(u4.y)};
#pragma unroll
        for (int P = 0; P < 8; ++P) {
            FDOT2(U2H(W0[ko + P]), hp[P],     acc[0]);
            FDOT2(U2H(W1[ko + P]), hp[P],     acc[1]);
            FDOT2(U2H(W0[ko + P]), hp[P + 1], acc[2]);
            FDOT2(U2H(W1[ko + P]), hp[P + 1], acc[3]);
        }
        c = u4; u1 = n1; u2 = n2; u3 = n3; u4 = n4;
    }
}

// 2 weight vectors -> 2 acc groups. 64 fdot2 / k.
static __device__ __forceinline__ void pass2(const uint* base,
                                             const uint* __restrict__ WA,
                                             const uint* __restrict__ WB,
                                             float* accA, float* accB) {
    const uint* WA1 = WA + WPP;
    const uint* WB1 = WB + WPP;
    uint2 c  = *(const uint2*)(base);
    uint2 u1 = *(const uint2*)(base + 2);
    uint2 u2 = *(const uint2*)(base + 4);
    uint2 u3 = *(const uint2*)(base + 6);
    uint2 u4 = *(const uint2*)(base + 8);
#pragma unroll 1
    for (int k = 0; k < 13; ++k) {
        const int ko = 8 * k;
        uint2 n1, n2, n3, n4;
        if (k < 12) {
            n1 = *(const uint2*)(base + ko + 10);
            n2 = *(const uint2*)(base + ko + 12);
            n3 = *(const uint2*)(base + ko + 14);
            n4 = *(const uint2*)(base + ko + 16);
        }
        h2 hp[10] = {U2H(c.x),  U2H(c.y),  U2H(u1.x), U2H(u1.y), U2H(u2.x),
                     U2H(u2.y), U2H(u3.x), U2H(u3.y), U2H(u4.x), U2H(u4.y)};
#pragma unroll
        for (int P = 0; P < 8; ++P) {
            FDOT2(U2H(WA[ko + P]),  hp[P],     accA[0]);
            FDOT2(U2H(WA1[ko + P]), hp[P],     accA[1]);
            FDOT2(U2H(WA[ko + P]),  hp[P + 1], accA[2]);
            FDOT2(U2H(WA1[ko + P]), hp[P + 1], accA[3]);
            FDOT2(U2H(WB[ko + P]),  hp[P],     accB[0]);
            FDOT2(U2H(WB1[ko + P]), hp[P],     accB[1]);
            FDOT2(U2H(WB[ko + P]),  hp[P + 1], accB[2]);
            FDOT2(U2H(WB1[ko + P]), hp[P + 1], accB[3]);
        }
        c = u4; u1 = n1; u2 = n2; u3 = n3; u4 = n4;
    }
}

// 4 weight vectors -> 4 acc groups. 128 fdot2 / k.
static __device__ __forceinline__ void pass4(const uint* base,
                                             const uint* __restrict__ WA,
                                             const uint* __restrict__ WB,
                                             const uint* __restrict__ WC,
                                             const uint* __restrict__ WD,
                                             float* accA, float* accB,
                                             float* accC, float* accD) {
    const uint* WA1 = WA + WPP; const uint* WB1 = WB + WPP;
    const uint* WC1 = WC + WPP; const uint* WD1 = WD + WPP;
    uint2 c  = *(const uint2*)(base);
    uint2 u1 = *(const uint2*)(base + 2);
    uint2 u2 = *(const uint2*)(base + 4);
    uint2 u3 = *(const uint2*)(base + 6);
    uint2 u4 = *(const uint2*)(base + 8);
#pragma unroll 1
    for (int k = 0; k < 13; ++k) {
        const int ko = 8 * k;
        uint2 n1, n2, n3, n4;
        if (k < 12) {
            n1 = *(const uint2*)(base + ko + 10);
            n2 = *(const uint2*)(base + ko + 12);
            n3 = *(const uint2*)(base + ko + 14);
            n4 = *(const uint2*)(base + ko + 16);
        }
        h2 hp[10] = {U2H(c.x),  U2H(c.y),  U2H(u1.x), U2H(u1.y), U2H(u2.x),
                     U2H(u2.y), U2H(u3.x), U2H(u3.y), U2H(u4.x), U2H(u4.y)};
#pragma unroll
        for (int P = 0; P < 8; ++P) {
            FDOT2(U2H(WA[ko + P]),  hp[P],     accA[0]);
            FDOT2(U2H(WB[ko + P]),  hp[P],     accB[0]);
            FDOT2(U2H(WC[ko + P]),  hp[P],     accC[0]);
            FDOT2(U2H(WD[ko + P]),  hp[P],     accD[0]);
            FDOT2(U2H(WA1[ko + P]), hp[P],     accA[1]);
            FDOT2(U2H(WB1[ko + P]), hp[P],     accB[1]);
            FDOT2(U2H(WC1[ko + P]), hp[P],     accC[1]);
            FDOT2(U2H(WD1[ko + P]), hp[P],     accD[1]);
            FDOT2(U2H(WA[ko + P]),  hp[P + 1], accA[2]);
            FDOT2(U2H(WB[ko + P]),  hp[P + 1], accB[2]);
            FDOT2(U2H(WC[ko + P]),  hp[P + 1], accC[2]);
            FDOT2(U2H(WD[ko + P]),  hp[P + 1], accD[2]);
            FDOT2(U2H(WA1[ko + P]), hp[P + 1], accA[3]);
            FDOT2(U2H(WB1[ko + P]), hp[P + 1], accB[3]);
            FDOT2(U2H(WC1[ko + P]), hp[P + 1], accC[3]);
            FDOT2(U2H(WD1[ko + P]), hp[P + 1], accD[3]);
        }
        c = u4; u1 = n1; u2 = n2; u3 = n3; u4 = n4;
    }
}

static __device__ __forceinline__ void calc_series(
        const _Float16 (*sxr)[XSTR], const _Float16 (*sxi)[XSTR], int pos, float* v) {
    const int ix = pos + 2;
    float x0r = (float)sxr[0][ix], x0i = (float)sxi[0][ix];
    float x1r = (float)sxr[1][ix], x1i = (float)sxi[1][ix];
    float p0 = x0r * x0r + x0i * x0i;
    float p1 = x1r * x1r + x1i * x1i;
    v[0] = 2.f * p0 + p1;
    v[1] = 2.f * p1 + p0;
    v[2] = x0r * x1r + x0i * x1i;       // qr
    v[3] = x0i * x1r - x0r * x1i;       // qi
#pragma unroll
    for (int sg = 0; sg < 2; ++sg) {
        const int jx = ix - (sg + 1);
        float a0r = (float)sxr[0][jx], a0i = (float)sxi[0][jx];
        float a1r = (float)sxr[1][jx], a1i = (float)sxi[1][jx];
        float U0r = x0r * a0r + x0i * a0i;
        float U0i = x0i * a0r - x0r * a0i;
        float U1r = x1r * a1r + x1i * a1i;
        float U1i = x1i * a1r - x1r * a1i;
        const int ba = 4 + sg * 8;
        v[ba + 0] = 2.f * U0r + U1r;
        v[ba + 1] = 2.f * U1r + U0r;
        v[ba + 2] = 2.f * U0i + U1i;
        v[ba + 3] = 2.f * U1i + U0i;
        v[ba + 4] = x0r * a1r + x0i * a1i;  // Br0
        v[ba + 5] = x1r * a0r + x1i * a0i;  // Br1
        v[ba + 6] = x0i * a1r - x0r * a1i;  // Bi0
        v[ba + 7] = x1i * a0r - x1r * a0i;  // Bi1
    }
}

__global__ __launch_bounds__(128, 3) void snse_kernel(
    const float* __restrict__ g_xr, const float* __restrict__ g_xi,
    const float* __restrict__ g_ti, const float* __restrict__ g_c00,
    const float* __restrict__ g_wx, const float* __restrict__ g_wc,
    const uint* __restrict__ Wg,
    float* __restrict__ g_out)
{
    __shared__ __align__(16) uint SE[NSER * SSTR];              // 19360 B
    __shared__ _Float16 s_xr_h[2][XSTR], s_xi_h[2][XSTR];       //  3712 B

    const int tid = threadIdx.x;
    const int b   = blockIdx.y;
    const int l0  = blockIdx.x * TL;

    const float tdb    = g_ti[b * 4 + 0];
    const float P      = expf(tdb * 0.23025850929940457f) * 0.5f;
    const float sP     = sqrtf(P);
    const float inv_sP = 1.0f / sP;
    const float C00    = g_c00[0];

    for (int idx = tid; idx < 2 * NPX; idx += 128) {
        int pidx = idx >> 1, ch = idx & 1;
        int m = l0 - 2 + pidx;
        int mw = m < 0 ? m + M_LEN : (m >= M_LEN ? m - M_LEN : m);
        int gg = (b * M_LEN + mw) * 2 + ch;
        s_xr_h[ch][pidx] = (_Float16)(g_xr[gg] * sP);
        s_xi_h[ch][pidx] = (_Float16)(g_xi[gg] * sP);
    }
    __syncthreads();

    // stage packed f16 series pairs; zero-fill beyond NPS (NaN guard)
    for (int p = tid; p < PAIRS; p += 128) {
        float v0[NSER], v1[NSER];
#pragma unroll
        for (int a = 0; a < NSER; ++a) { v0[a] = 0.f; v1[a] = 0.f; }
        const int m0 = 2 * p, m1 = 2 * p + 1;
        if (m0 < NPS) calc_series(s_xr_h, s_xi_h, m0, v0);
        if (m1 < NPS) calc_series(s_xr_h, s_xi_h, m1, v1);
#pragma unroll
        for (int a = 0; a < NSER; ++a)
            SE[a * SSTR + p] = H2U(__builtin_amdgcn_cvt_pkrtz(v0[a], v1[a]));
    }
    __syncthreads();

    const int g  = tid & 63;
    const int nn = tid >> 6;
    const int r  = g << 2;
    const int pb = g << 1;

    float acc_ix[4] = {}, acc_qr[4] = {}, acc_qi[4] = {};
    float fAr[4][4] = {}, fAi[4][4] = {}, fBr[4][4] = {}, fBi[4][4] = {};

    // series-major passes
    pass1(&SE[nn * SSTR + pb], Wg + 0 * WPP, acc_ix);   // ps ch=nn, wx
    pass1(&SE[2 * SSTR + pb],  Wg + 2 * WPP, acc_qr);   // qr, wc
    pass1(&SE[3 * SSTR + pb],  Wg + 2 * WPP, acc_qi);   // qi, wc

#pragma unroll 1
    for (int sg = 0; sg < 2; ++sg) {
        const int sip = 2 + sg, sin_ = 1 - sg;
        const int ba = 4 + sg * 8;
        const uint* G = Wg + (4 + sg * 12) * WPP;
        // weight vectors in G: +0 wPr, +2 wPi, +4 wNr, +6 wNi, +8 nWpi, +10 nWnr
        const uint* bAr  = &SE[(ba + 0 + nn) * SSTR + pb];
        const uint* bAi  = &SE[(ba + 2 + nn) * SSTR + pb];
        const uint* bBor = &SE[(ba + 4 + nn) * SSTR + pb];
        const uint* bBoi = &SE[(ba + 6 + nn) * SSTR + pb];
        const uint* bBxr = &SE[(ba + 4 + (1 - nn)) * SSTR + pb];
        const uint* bBxi = &SE[(ba + 6 + (1 - nn)) * SSTR + pb];

        // A real window: wPr->pR, wPi->pI, wNr->nR, wNi->nI
        pass4(bAr, G + 0 * WPP, G + 2 * WPP, G + 4 * WPP, G + 6 * WPP,
              fAr[sip], fAi[sip], fAr[sin_], fAi[sin_]);
        // A imag window: -wPi->pR, wPr->pI, wNi->nR, -wNr->nI
        pass4(bAi, G + 8 * WPP, G + 0 * WPP, G + 6 * WPP, G + 10 * WPP,
              fAr[sip], fAi[sip], fAr[sin_], fAi[sin_]);
        // B own-ch real: wPr->pR, wPi->pI
        pass2(bBor, G + 0 * WPP, G + 2 * WPP, fBr[sip], fBi[sip]);
        // B own-ch imag: -wPi->pR, wPr->pI
        pass2(bBoi, G + 8 * WPP, G + 0 * WPP, fBr[sip], fBi[sip]);
        // B other-ch real (minus rule): wNr->nR, wNi->nI
        pass2(bBxr, G + 4 * WPP, G + 6 * WPP, fBr[sin_], fBi[sin_]);
        // B other-ch imag: wNi->nR, -wNr->nI
        pass2(bBxi, G + 6 * WPP, G + 10 * WPP, fBr[sin_], fBi[sin_]);
    }

    // zero-center-tap correction (zcv only); f16-rounded weights to match conv
    {
        const float wx100 = (float)(_Float16)g_wx[T_HALF];
        const float wc100 = (float)(_Float16)g_wc[T_HALF];
#pragma unroll
        for (int o = 0; o < 4; ++o) {
            const int pos = r + o + T_HALF;
            const int pp = pos >> 1, pe = pos & 1;
            h2 vps = U2H(SE[nn * SSTR + pp]);
            h2 vqr = U2H(SE[2 * SSTR + pp]);
            h2 vqi = U2H(SE[3 * SSTR + pp]);
            acc_ix[o] = fmaf(-wx100, (float)vps[pe], acc_ix[o]);
            acc_qr[o] = fmaf(-wc100, (float)vqr[pe], acc_qr[o]);
            acc_qi[o] = fmaf(-wc100, (float)vqi[pe], acc_qi[o]);
        }
    }

    // epilogue
    const int ssf[4] = {-2, -1, 1, 2};
#pragma unroll
    for (int o = 0; o < 4; ++o) {
        const int lrel = r + o;
        const int l = l0 + lrel;
        const int xc = lrel + T_HALF + 2;
        float X0r = (float)s_xr_h[0][xc], X0i = (float)s_xi_h[0][xc];
        float X1r = (float)s_xr_h[1][xc], X1i = (float)s_xi_h[1][xc];
        float pw  = X0r * X0r + X0i * X0i + X1r * X1r + X1i * X1i;
        float phi = C00 * pw + 2.f * acc_ix[o];
        float sph, cph;
        __sincosf(phi, &sph, &cph);
        float qcr = acc_qr[o];
        float qci = nn ? -acc_qi[o] : acc_qi[o];
        float br_ = nn ? X1r : X0r, bi_ = nn ? X1i : X0i;
        float or_ = nn ? X0r : X1r, oi_ = nn ? X0i : X1i;
        float ici_r = -(or_ * qci + oi_ * qcr);
        float ici_i =   or_ * qcr - oi_ * qci;
        float fw_r = 0.f, fw_i = 0.f;
#pragma unroll
        for (int si = 0; si < 4; ++si) {
            int sx = xc - ssf[si];
            float xnr  = (float)s_xr_h[nn][sx],     xni = (float)s_xi_h[nn][sx];
            float xor_ = (float)s_xr_h[1 - nn][sx], xoi = (float)s_xi_h[1 - nn][sx];
            fw_r += xnr * fAr[si][o] - xni * fAi[si][o]
                  + xor_ * fBr[si][o] - xoi * fBi[si][o];
            fw_i += xnr * fAi[si][o] + xni * fAr[si][o]
                  + xor_ * fBi[si][o] + xoi * fBr[si][o];
        }
        float out_r = br_ * cph - bi_ * sph + ici_r + fw_r;
        float out_i = br_ * sph + bi_ * cph + ici_i + fw_i;
        if (l < L_OUT) {
            int oidx = (((b * L_OUT) + l) * 2 + nn) * 2;
            g_out[oidx]     = out_r * inv_sP;
            g_out[oidx + 1] = out_i * inv_sP;
        }
    }
}

extern "C" void kernel_launch(void* const* d_in, const int* in_sizes, int n_in,
                              void* d_out, int out_size, void* d_ws, size_t ws_size,
                              hipStream_t stream) {
    const float* xr  = (const float*)d_in[0];
    const float* xi  = (const float*)d_in[1];
    const float* ti  = (const float*)d_in[2];
    const float* c00 = (const float*)d_in[3];
    const float* wx  = (const float*)d_in[4];
    const float* wc  = (const float*)d_in[5];
    const float* wr  = (const float*)d_in[6];
    const float* wi  = (const float*)d_in[7];
    float* out = (float*)d_out;
    uint* W = (uint*)d_ws;   // NWARR*WPP*4 = 11648 bytes

    prep_weights<<<dim3((NWARR * WPP + 255) / 256), dim3(256), 0, stream>>>(wx, wc, wr, wi, W);

    dim3 grid(NTILES, B_SZ, 1);
    dim3 block(128, 1, 1);
    snse_kernel<<<grid, block, 0, stream>>>(xr, xi, ti, c00, wx, wc, W, out);
}

// Round 8
// 281.702 us; speedup vs baseline: 2.1523x; 2.1523x over previous
//
#include <hip/hip_runtime.h>
#include <math.h>

#define M_LEN 40000
#define B_SZ 16
#define K_TAPS 201
#define T_HALF 100
#define L_OUT 39800          // M_LEN - K_TAPS + 1
#define TL 256               // outputs per block
#define NTILES 156           // ceil(L_OUT / TL)
#define NP 456               // TL + K_TAPS - 1
#define NPS 458              // NP + 2 : staged series positions
#define NPX 460              // NP + 4 : x positions
#define XSTR 464             // x f16 stride
#define PAIRS 240            // staged series pairs (max read index 231)
#define SSTR 242             // series pair-array stride in dwords (even!)
#define NSER 20
#define WPP 104              // weight pairs per array (208 taps)
#define NWARR 28             // 4 base + 2 sg x 12

typedef unsigned int uint;
typedef __fp16 h2 __attribute__((ext_vector_type(2)));

static __device__ __forceinline__ h2 U2H(uint u){ h2 r; __builtin_memcpy(&r,&u,4); return r; }
static __device__ __forceinline__ uint H2U(h2 h){ uint r; __builtin_memcpy(&r,&h,4); return r; }

#define FDOT2(w,v,acc) (acc) = __builtin_amdgcn_fdot2((w),(v),(acc),false)

// ---------------- prep kernel -------------------------------------------------
// Global weight array layout (each WPP uints): 0 wx_v0, 1 wx_v1, 2 wc_v0, 3 wc_v1,
// then per sg block at 4+sg*12: kind pairs (v0,v1) for
// kind 0 wPr, 1 wPi, 2 wNr, 3 wNi, 4 nWpi(=-wPi), 5 nWnr(=-wNr)
// version 0: pair p = (w[2p], w[2p+1]); version 1: (w[2p-1], w[2p])
static __device__ float wkind(int kind, int sg, int t,
                              const float* wr, const float* wi) {
    if (kind == 0) return (t >= 0 && t <= 200) ? wr[(2 + sg) * K_TAPS + t] : 0.f;
    if (kind == 1) return (t >= 0 && t <= 200) ? wi[(2 + sg) * K_TAPS + t] : 0.f;
    int tt = t - (sg + 1);
    if (kind == 2) return (tt >= 0 && tt <= 200) ? wr[(1 - sg) * K_TAPS + tt] : 0.f;
    if (kind == 3) return (tt >= 0 && tt <= 200) ? wi[(1 - sg) * K_TAPS + tt] : 0.f;
    if (kind == 4) return -wkind(1, sg, t, wr, wi);
    return -wkind(2, sg, t, wr, wi);
}

__global__ void prep_weights(const float* __restrict__ wx, const float* __restrict__ wc,
                             const float* __restrict__ wr, const float* __restrict__ wi,
                             uint* __restrict__ W) {
    int idx = blockIdx.x * 256 + threadIdx.x;
    if (idx >= NWARR * WPP) return;
    int p = idx % WPP;
    int a = idx / WPP;
    float f0, f1;
    if (a < 4) {
        int ver = a & 1;
        const float* src = (a < 2) ? wx : wc;
        int t0 = 2 * p - ver;
        f0 = (t0     >= 0 && t0     <= 200) ? src[t0]     : 0.f;
        f1 = (t0 + 1 >= 0 && t0 + 1 <= 200) ? src[t0 + 1] : 0.f;
    } else {
        int q = a - 4;
        int sg = q / 12, r = q % 12;
        int kind = r >> 1, ver = r & 1;
        int t0 = 2 * p - ver;
        f0 = wkind(kind, sg, t0,     wr, wi);
        f1 = wkind(kind, sg, t0 + 1, wr, wi);
    }
    W[idx] = H2U(__builtin_amdgcn_cvt_pkrtz(f0, f1));
}

// ---------------- conv passes (series-major) ----------------------------------
// Window for tap-block k covers pairs [8k .. 8k+9] relative to thread base.
// hp[t] (t=0..9) = pair (base_pos + 2(8k+t)).  Outputs o: even use v0 weights,
// odd use v1 (shifted) weights; o>=2 use hp[.+1].

// 1 weight vector (v0 at W0, v1 at W0+WPP) -> 4 accs. 32 fdot2 / k.
static __device__ __forceinline__ void pass1(const uint* base, const uint* __restrict__ W0,
                                             float* acc) {
    const uint* W1 = W0 + WPP;
    uint2 c  = *(const uint2*)(base);
    uint2 u1 = *(const uint2*)(base + 2);
    uint2 u2 = *(const uint2*)(base + 4);
    uint2 u3 = *(const uint2*)(base + 6);
    uint2 u4 = *(const uint2*)(base + 8);
#pragma unroll 1
    for (int k = 0; k < 13; ++k) {
        const int ko = 8 * k;
        uint2 n1, n2, n3, n4;
        if (k < 12) {
            n1 = *(const uint2*)(base + ko + 10);
            n2 = *(const uint2*)(base + ko + 12);
            n3 = *(const uint2*)(base + ko + 14);
            n4 = *(const uint2*)(base + ko + 16);
        }
        h2 hp[10] = {U2H(c.x),  U2H(c.y),  U2H(u1.x), U2H(u1.y), U2H(u2.x),
                     U2H(u2.y), U2H(u3.x), U2H(u3.y), U2H(u4.x), U2H(u4.y)};
#pragma unroll
        for (int P = 0; P < 8; ++P) {
            FDOT2(U2H(W0[ko + P]), hp[P],     acc[0]);
            FDOT2(U2H(W1[ko + P]), hp[P],     acc[1]);
            FDOT2(U2H(W0[ko + P]), hp[P + 1], acc[2]);
            FDOT2(U2H(W1[ko + P]), hp[P + 1], acc[3]);
        }
        c = u4; u1 = n1; u2 = n2; u3 = n3; u4 = n4;
    }
}

// 2 weight vectors -> 2 acc groups. 64 fdot2 / k.
static __device__ __forceinline__ void pass2(const uint* base,
                                             const uint* __restrict__ WA,
                                             const uint* __restrict__ WB,
                                             float* accA, float* accB) {
    const uint* WA1 = WA + WPP;
    const uint* WB1 = WB + WPP;
    uint2 c  = *(const uint2*)(base);
    uint2 u1 = *(const uint2*)(base + 2);
    uint2 u2 = *(const uint2*)(base + 4);
    uint2 u3 = *(const uint2*)(base + 6);
    uint2 u4 = *(const uint2*)(base + 8);
#pragma unroll 1
    for (int k = 0; k < 13; ++k) {
        const int ko = 8 * k;
        uint2 n1, n2, n3, n4;
        if (k < 12) {
            n1 = *(const uint2*)(base + ko + 10);
            n2 = *(const uint2*)(base + ko + 12);
            n3 = *(const uint2*)(base + ko + 14);
            n4 = *(const uint2*)(base + ko + 16);
        }
        h2 hp[10] = {U2H(c.x),  U2H(c.y),  U2H(u1.x), U2H(u1.y), U2H(u2.x),
                     U2H(u2.y), U2H(u3.x), U2H(u3.y), U2H(u4.x), U2H(u4.y)};
#pragma unroll
        for (int P = 0; P < 8; ++P) {
            FDOT2(U2H(WA[ko + P]),  hp[P],     accA[0]);
            FDOT2(U2H(WA1[ko + P]), hp[P],     accA[1]);
            FDOT2(U2H(WA[ko + P]),  hp[P + 1], accA[2]);
            FDOT2(U2H(WA1[ko + P]), hp[P + 1], accA[3]);
            FDOT2(U2H(WB[ko + P]),  hp[P],     accB[0]);
            FDOT2(U2H(WB1[ko + P]), hp[P],     accB[1]);
            FDOT2(U2H(WB[ko + P]),  hp[P + 1], accB[2]);
            FDOT2(U2H(WB1[ko + P]), hp[P + 1], accB[3]);
        }
        c = u4; u1 = n1; u2 = n2; u3 = n3; u4 = n4;
    }
}

// 4 weight vectors -> 4 acc groups. 128 fdot2 / k.
static __device__ __forceinline__ void pass4(const uint* base,
                                             const uint* __restrict__ WA,
                                             const uint* __restrict__ WB,
                                             const uint* __restrict__ WC,
                                             const uint* __restrict__ WD,
                                             float* accA, float* accB,
                                             float* accC, float* accD) {
    const uint* WA1 = WA + WPP; const uint* WB1 = WB + WPP;
    const uint* WC1 = WC + WPP; const uint* WD1 = WD + WPP;
    uint2 c  = *(const uint2*)(base);
    uint2 u1 = *(const uint2*)(base + 2);
    uint2 u2 = *(const uint2*)(base + 4);
    uint2 u3 = *(const uint2*)(base + 6);
    uint2 u4 = *(const uint2*)(base + 8);
#pragma unroll 1
    for (int k = 0; k < 13; ++k) {
        const int ko = 8 * k;
        uint2 n1, n2, n3, n4;
        if (k < 12) {
            n1 = *(const uint2*)(base + ko + 10);
            n2 = *(const uint2*)(base + ko + 12);
            n3 = *(const uint2*)(base + ko + 14);
            n4 = *(const uint2*)(base + ko + 16);
        }
        h2 hp[10] = {U2H(c.x),  U2H(c.y),  U2H(u1.x), U2H(u1.y), U2H(u2.x),
                     U2H(u2.y), U2H(u3.x), U2H(u3.y), U2H(u4.x), U2H(u4.y)};
#pragma unroll
        for (int P = 0; P < 8; ++P) {
            FDOT2(U2H(WA[ko + P]),  hp[P],     accA[0]);
            FDOT2(U2H(WB[ko + P]),  hp[P],     accB[0]);
            FDOT2(U2H(WC[ko + P]),  hp[P],     accC[0]);
            FDOT2(U2H(WD[ko + P]),  hp[P],     accD[0]);
            FDOT2(U2H(WA1[ko + P]), hp[P],     accA[1]);
            FDOT2(U2H(WB1[ko + P]), hp[P],     accB[1]);
            FDOT2(U2H(WC1[ko + P]), hp[P],     accC[1]);
            FDOT2(U2H(WD1[ko + P]), hp[P],     accD[1]);
            FDOT2(U2H(WA[ko + P]),  hp[P + 1], accA[2]);
            FDOT2(U2H(WB[ko + P]),  hp[P + 1], accB[2]);
            FDOT2(U2H(WC[ko + P]),  hp[P + 1], accC[2]);
            FDOT2(U2H(WD[ko + P]),  hp[P + 1], accD[2]);
            FDOT2(U2H(WA1[ko + P]), hp[P + 1], accA[3]);
            FDOT2(U2H(WB1[ko + P]), hp[P + 1], accB[3]);
            FDOT2(U2H(WC1[ko + P]), hp[P + 1], accC[3]);
            FDOT2(U2H(WD1[ko + P]), hp[P + 1], accD[3]);
        }
        c = u4; u1 = n1; u2 = n2; u3 = n3; u4 = n4;
    }
}

static __device__ __forceinline__ void calc_series(
        const _Float16 (*sxr)[XSTR], const _Float16 (*sxi)[XSTR], int pos, float* v) {
    const int ix = pos + 2;
    float x0r = (float)sxr[0][ix], x0i = (float)sxi[0][ix];
    float x1r = (float)sxr[1][ix], x1i = (float)sxi[1][ix];
    float p0 = x0r * x0r + x0i * x0i;
    float p1 = x1r * x1r + x1i * x1i;
    v[0] = 2.f * p0 + p1;
    v[1] = 2.f * p1 + p0;
    v[2] = x0r * x1r + x0i * x1i;       // qr
    v[3] = x0i * x1r - x0r * x1i;       // qi
#pragma unroll
    for (int sg = 0; sg < 2; ++sg) {
        const int jx = ix - (sg + 1);
        float a0r = (float)sxr[0][jx], a0i = (float)sxi[0][jx];
        float a1r = (float)sxr[1][jx], a1i = (float)sxi[1][jx];
        float U0r = x0r * a0r + x0i * a0i;
        float U0i = x0i * a0r - x0r * a0i;
        float U1r = x1r * a1r + x1i * a1i;
        float U1i = x1i * a1r - x1r * a1i;
        const int ba = 4 + sg * 8;
        v[ba + 0] = 2.f * U0r + U1r;
        v[ba + 1] = 2.f * U1r + U0r;
        v[ba + 2] = 2.f * U0i + U1i;
        v[ba + 3] = 2.f * U1i + U0i;
        v[ba + 4] = x0r * a1r + x0i * a1i;  // Br0
        v[ba + 5] = x1r * a0r + x1i * a0i;  // Br1
        v[ba + 6] = x0i * a1r - x0r * a1i;  // Bi0
        v[ba + 7] = x1i * a0r - x1r * a0i;  // Bi1
    }
}

__global__ __launch_bounds__(128, 3) void snse_kernel(
    const float* __restrict__ g_xr, const float* __restrict__ g_xi,
    const float* __restrict__ g_ti, const float* __restrict__ g_c00,
    const float* __restrict__ g_wx, const float* __restrict__ g_wc,
    const uint* __restrict__ Wg,
    float* __restrict__ g_out)
{
    __shared__ __align__(16) uint SE[NSER * SSTR];              // 19360 B
    __shared__ _Float16 s_xr_h[2][XSTR], s_xi_h[2][XSTR];       //  3712 B

    const int tid = threadIdx.x;
    const int b   = blockIdx.y;
    const int l0  = blockIdx.x * TL;

    const float tdb    = g_ti[b * 4 + 0];
    const float P      = expf(tdb * 0.23025850929940457f) * 0.5f;
    const float sP     = sqrtf(P);
    const float inv_sP = 1.0f / sP;
    const float C00    = g_c00[0];

    for (int idx = tid; idx < 2 * NPX; idx += 128) {
        int pidx = idx >> 1, ch = idx & 1;
        int m = l0 - 2 + pidx;
        int mw = m < 0 ? m + M_LEN : (m >= M_LEN ? m - M_LEN : m);
        int gg = (b * M_LEN + mw) * 2 + ch;
        s_xr_h[ch][pidx] = (_Float16)(g_xr[gg] * sP);
        s_xi_h[ch][pidx] = (_Float16)(g_xi[gg] * sP);
    }
    __syncthreads();

    // stage packed f16 series pairs; zero-fill beyond NPS (NaN guard)
    for (int p = tid; p < PAIRS; p += 128) {
        float v0[NSER], v1[NSER];
#pragma unroll
        for (int a = 0; a < NSER; ++a) { v0[a] = 0.f; v1[a] = 0.f; }
        const int m0 = 2 * p, m1 = 2 * p + 1;
        if (m0 < NPS) calc_series(s_xr_h, s_xi_h, m0, v0);
        if (m1 < NPS) calc_series(s_xr_h, s_xi_h, m1, v1);
#pragma unroll
        for (int a = 0; a < NSER; ++a)
            SE[a * SSTR + p] = H2U(__builtin_amdgcn_cvt_pkrtz(v0[a], v1[a]));
    }
    __syncthreads();

    const int g  = tid & 63;
    const int nn = tid >> 6;
    const int r  = g << 2;
    const int pb = g << 1;

    float acc_ix[4] = {}, acc_qr[4] = {}, acc_qi[4] = {};
    float fAr[4][4] = {}, fAi[4][4] = {}, fBr[4][4] = {}, fBi[4][4] = {};

    // series-major passes
    pass1(&SE[nn * SSTR + pb], Wg + 0 * WPP, acc_ix);   // ps ch=nn, wx
    pass1(&SE[2 * SSTR + pb],  Wg + 2 * WPP, acc_qr);   // qr, wc
    pass1(&SE[3 * SSTR + pb],  Wg + 2 * WPP, acc_qi);   // qi, wc

    // sg FULLY UNROLLED: all accumulator indices must be compile-time
    // constants or fAr/fBr land in scratch (R7: 81 MB WRITE_SIZE, 60 VGPR).
#pragma unroll
    for (int sg = 0; sg < 2; ++sg) {
        const int sip = 2 + sg, sin_ = 1 - sg;
        const int ba = 4 + sg * 8;
        const uint* G = Wg + (4 + sg * 12) * WPP;
        // weight vectors in G: +0 wPr, +2 wPi, +4 wNr, +6 wNi, +8 nWpi, +10 nWnr
        const uint* bAr  = &SE[(ba + 0 + nn) * SSTR + pb];
        const uint* bAi  = &SE[(ba + 2 + nn) * SSTR + pb];
        const uint* bBor = &SE[(ba + 4 + nn) * SSTR + pb];
        const uint* bBoi = &SE[(ba + 6 + nn) * SSTR + pb];
        const uint* bBxr = &SE[(ba + 4 + (1 - nn)) * SSTR + pb];
        const uint* bBxi = &SE[(ba + 6 + (1 - nn)) * SSTR + pb];

        // A real window: wPr->pR, wPi->pI, wNr->nR, wNi->nI
        pass4(bAr, G + 0 * WPP, G + 2 * WPP, G + 4 * WPP, G + 6 * WPP,
              fAr[sip], fAi[sip], fAr[sin_], fAi[sin_]);
        // A imag window: -wPi->pR, wPr->pI, wNi->nR, -wNr->nI
        pass4(bAi, G + 8 * WPP, G + 0 * WPP, G + 6 * WPP, G + 10 * WPP,
              fAr[sip], fAi[sip], fAr[sin_], fAi[sin_]);
        // B own-ch real: wPr->pR, wPi->pI
        pass2(bBor, G + 0 * WPP, G + 2 * WPP, fBr[sip], fBi[sip]);
        // B own-ch imag: -wPi->pR, wPr->pI
        pass2(bBoi, G + 8 * WPP, G + 0 * WPP, fBr[sip], fBi[sip]);
        // B other-ch real (minus rule): wNr->nR, wNi->nI
        pass2(bBxr, G + 4 * WPP, G + 6 * WPP, fBr[sin_], fBi[sin_]);
        // B other-ch imag: wNi->nR, -wNr->nI
        pass2(bBxi, G + 6 * WPP, G + 10 * WPP, fBr[sin_], fBi[sin_]);
    }

    // zero-center-tap correction (zcv only); f16-rounded weights to match conv
    {
        const float wx100 = (float)(_Float16)g_wx[T_HALF];
        const float wc100 = (float)(_Float16)g_wc[T_HALF];
#pragma unroll
        for (int o = 0; o < 4; ++o) {
            const int pos = r + o + T_HALF;
            const int pp = pos >> 1, pe = pos & 1;
            h2 vps = U2H(SE[nn * SSTR + pp]);
            h2 vqr = U2H(SE[2 * SSTR + pp]);
            h2 vqi = U2H(SE[3 * SSTR + pp]);
            acc_ix[o] = fmaf(-wx100, (float)vps[pe], acc_ix[o]);
            acc_qr[o] = fmaf(-wc100, (float)vqr[pe], acc_qr[o]);
            acc_qi[o] = fmaf(-wc100, (float)vqi[pe], acc_qi[o]);
        }
    }

    // epilogue
    const int ssf[4] = {-2, -1, 1, 2};
#pragma unroll
    for (int o = 0; o < 4; ++o) {
        const int lrel = r + o;
        const int l = l0 + lrel;
        const int xc = lrel + T_HALF + 2;
        float X0r = (float)s_xr_h[0][xc], X0i = (float)s_xi_h[0][xc];
        float X1r = (float)s_xr_h[1][xc], X1i = (float)s_xi_h[1][xc];
        float pw  = X0r * X0r + X0i * X0i + X1r * X1r + X1i * X1i;
        float phi = C00 * pw + 2.f * acc_ix[o];
        float sph, cph;
        __sincosf(phi, &sph, &cph);
        float qcr = acc_qr[o];
        float qci = nn ? -acc_qi[o] : acc_qi[o];
        float br_ = nn ? X1r : X0r, bi_ = nn ? X1i : X0i;
        float or_ = nn ? X0r : X1r, oi_ = nn ? X0i : X1i;
        float ici_r = -(or_ * qci + oi_ * qcr);
        float ici_i =   or_ * qcr - oi_ * qci;
        float fw_r = 0.f, fw_i = 0.f;
#pragma unroll
        for (int si = 0; si < 4; ++si) {
            int sx = xc - ssf[si];
            float xnr  = (float)s_xr_h[nn][sx],     xni = (float)s_xi_h[nn][sx];
            float xor_ = (float)s_xr_h[1 - nn][sx], xoi = (float)s_xi_h[1 - nn][sx];
            fw_r += xnr * fAr[si][o] - xni * fAi[si][o]
                  + xor_ * fBr[si][o] - xoi * fBi[si][o];
            fw_i += xnr * fAi[si][o] + xni * fAr[si][o]
                  + xor_ * fBi[si][o] + xoi * fBr[si][o];
        }
        float out_r = br_ * cph - bi_ * sph + ici_r + fw_r;
        float out_i = br_ * sph + bi_ * cph + ici_i + fw_i;
        if (l < L_OUT) {
            int oidx = (((b * L_OUT) + l) * 2 + nn) * 2;
            g_out[oidx]     = out_r * inv_sP;
            g_out[oidx + 1] = out_i * inv_sP;
        }
    }
}

extern "C" void kernel_launch(void* const* d_in, const int* in_sizes, int n_in,
                              void* d_out, int out_size, void* d_ws, size_t ws_size,
                              hipStream_t stream) {
    const float* xr  = (const float*)d_in[0];
    const float* xi  = (const float*)d_in[1];
    const float* ti  = (const float*)d_in[2];
    const float* c00 = (const float*)d_in[3];
    const float* wx  = (const float*)d_in[4];
    const float* wc  = (const float*)d_in[5];
    const float* wr  = (const float*)d_in[6];
    const float* wi  = (const float*)d_in[7];
    float* out = (float*)d_out;
    uint* W = (uint*)d_ws;   // NWARR*WPP*4 = 11648 bytes

    prep_weights<<<dim3((NWARR * WPP + 255) / 256), dim3(256), 0, stream>>>(wx, wc, wr, wi, W);

    dim3 grid(NTILES, B_SZ, 1);
    dim3 block(128, 1, 1);
    snse_kernel<<<grid, block, 0, stream>>>(xr, xi, ti, c00, wx, wc, W, out);
}

// Round 9
// 243.973 us; speedup vs baseline: 2.4851x; 1.1546x over previous
//
#include <hip/hip_runtime.h>
#include <math.h>

#define M_LEN 40000
#define B_SZ 16
#define K_TAPS 201
#define T_HALF 100
#define L_OUT 39800          // M_LEN - K_TAPS + 1
#define TL 512               // outputs per block
#define NTILES 78            // ceil(L_OUT / TL)
#define NP 712               // TL + K_TAPS - 1
#define NPS 714              // NP + 2 : staged series positions
#define NPX 716              // NP + 4 : x positions
#define XSTR 720             // x f16 stride
#define PAIRS 360            // staged series pairs (max read index 359)
#define SSTR 362             // series pair-array stride in dwords (even)
#define NSER 20
#define WPP 104              // weight pairs per array (208 taps)
#define NWARR 28             // 4 base + 2 sg x 12

typedef unsigned int uint;
typedef __fp16 h2 __attribute__((ext_vector_type(2)));

static __device__ __forceinline__ h2 U2H(uint u){ h2 r; __builtin_memcpy(&r,&u,4); return r; }
static __device__ __forceinline__ uint H2U(h2 h){ uint r; __builtin_memcpy(&r,&h,4); return r; }

#define FDOT2(w,v,acc) (acc) = __builtin_amdgcn_fdot2((w),(v),(acc),false)

// ---------------- prep kernel -------------------------------------------------
// Weight arrays (WPP uints each): 0 wx_v0, 1 wx_v1, 2 wc_v0, 3 wc_v1,
// then per sg block at 4+sg*12: kind pairs (v0,v1) for
// kind 0 wPr, 1 wPi, 2 wNr, 3 wNi, 4 nWpi(=-wPi), 5 nWnr(=-wNr)
// version 0: pair p = (w[2p], w[2p+1]); version 1: (w[2p-1], w[2p])
static __device__ float wkind(int kind, int sg, int t,
                              const float* wr, const float* wi) {
    if (kind == 0) return (t >= 0 && t <= 200) ? wr[(2 + sg) * K_TAPS + t] : 0.f;
    if (kind == 1) return (t >= 0 && t <= 200) ? wi[(2 + sg) * K_TAPS + t] : 0.f;
    int tt = t - (sg + 1);
    if (kind == 2) return (tt >= 0 && tt <= 200) ? wr[(1 - sg) * K_TAPS + tt] : 0.f;
    if (kind == 3) return (tt >= 0 && tt <= 200) ? wi[(1 - sg) * K_TAPS + tt] : 0.f;
    if (kind == 4) return -wkind(1, sg, t, wr, wi);
    return -wkind(2, sg, t, wr, wi);
}

__global__ void prep_weights(const float* __restrict__ wx, const float* __restrict__ wc,
                             const float* __restrict__ wr, const float* __restrict__ wi,
                             uint* __restrict__ W) {
    int idx = blockIdx.x * 256 + threadIdx.x;
    if (idx >= NWARR * WPP) return;
    int p = idx % WPP;
    int a = idx / WPP;
    float f0, f1;
    if (a < 4) {
        int ver = a & 1;
        const float* src = (a < 2) ? wx : wc;
        int t0 = 2 * p - ver;
        f0 = (t0     >= 0 && t0     <= 200) ? src[t0]     : 0.f;
        f1 = (t0 + 1 >= 0 && t0 + 1 <= 200) ? src[t0 + 1] : 0.f;
    } else {
        int q = a - 4;
        int sg = q / 12, r = q % 12;
        int kind = r >> 1, ver = r & 1;
        int t0 = 2 * p - ver;
        f0 = wkind(kind, sg, t0,     wr, wi);
        f1 = wkind(kind, sg, t0 + 1, wr, wi);
    }
    W[idx] = H2U(__builtin_amdgcn_cvt_pkrtz(f0, f1));
}

// ---------------- window + dot helpers ----------------------------------------
// Window for tap-block k covers pairs [8k .. 8k+8] (hp[0..8] used).
struct Win10 { h2 hp[10]; };

static __device__ __forceinline__ Win10 readwin(const uint* base, int ko) {
    Win10 w;
    uint2 u0 = *(const uint2*)(base + ko);
    uint2 u1 = *(const uint2*)(base + ko + 2);
    uint2 u2 = *(const uint2*)(base + ko + 4);
    uint2 u3 = *(const uint2*)(base + ko + 6);
    uint2 u4 = *(const uint2*)(base + ko + 8);
    w.hp[0] = U2H(u0.x); w.hp[1] = U2H(u0.y);
    w.hp[2] = U2H(u1.x); w.hp[3] = U2H(u1.y);
    w.hp[4] = U2H(u2.x); w.hp[5] = U2H(u2.y);
    w.hp[6] = U2H(u3.x); w.hp[7] = U2H(u3.y);
    w.hp[8] = U2H(u4.x); w.hp[9] = U2H(u4.y);
    return w;
}

// 1 weight vector (v0 at W0, v1 at W0+WPP) -> 4 accs. 32 fdot2.
static __device__ __forceinline__ void dot1(const Win10& W, const uint* __restrict__ W0,
                                            int ko, float* acc) {
    const uint* W1 = W0 + WPP;
#pragma unroll
    for (int P = 0; P < 8; ++P) {
        FDOT2(U2H(W0[ko + P]), W.hp[P],     acc[0]);
        FDOT2(U2H(W1[ko + P]), W.hp[P],     acc[1]);
        FDOT2(U2H(W0[ko + P]), W.hp[P + 1], acc[2]);
        FDOT2(U2H(W1[ko + P]), W.hp[P + 1], acc[3]);
    }
}

// 2 weight vectors -> 2 acc groups. 64 fdot2.
static __device__ __forceinline__ void dot2w(const Win10& W,
                                             const uint* __restrict__ WA,
                                             const uint* __restrict__ WB,
                                             int ko, float* accA, float* accB) {
    const uint* WA1 = WA + WPP; const uint* WB1 = WB + WPP;
#pragma unroll
    for (int P = 0; P < 8; ++P) {
        FDOT2(U2H(WA[ko + P]),  W.hp[P],     accA[0]);
        FDOT2(U2H(WA1[ko + P]), W.hp[P],     accA[1]);
        FDOT2(U2H(WA[ko + P]),  W.hp[P + 1], accA[2]);
        FDOT2(U2H(WA1[ko + P]), W.hp[P + 1], accA[3]);
        FDOT2(U2H(WB[ko + P]),  W.hp[P],     accB[0]);
        FDOT2(U2H(WB1[ko + P]), W.hp[P],     accB[1]);
        FDOT2(U2H(WB[ko + P]),  W.hp[P + 1], accB[2]);
        FDOT2(U2H(WB1[ko + P]), W.hp[P + 1], accB[3]);
    }
}

// 4 weight vectors -> 4 acc groups. 128 fdot2.
static __device__ __forceinline__ void dot4w(const Win10& W,
                                             const uint* __restrict__ WA,
                                             const uint* __restrict__ WB,
                                             const uint* __restrict__ WC,
                                             const uint* __restrict__ WD,
                                             int ko, float* accA, float* accB,
                                             float* accC, float* accD) {
    const uint* WA1 = WA + WPP; const uint* WB1 = WB + WPP;
    const uint* WC1 = WC + WPP; const uint* WD1 = WD + WPP;
#pragma unroll
    for (int P = 0; P < 8; ++P) {
        FDOT2(U2H(WA[ko + P]),  W.hp[P],     accA[0]);
        FDOT2(U2H(WB[ko + P]),  W.hp[P],     accB[0]);
        FDOT2(U2H(WC[ko + P]),  W.hp[P],     accC[0]);
        FDOT2(U2H(WD[ko + P]),  W.hp[P],     accD[0]);
        FDOT2(U2H(WA1[ko + P]), W.hp[P],     accA[1]);
        FDOT2(U2H(WB1[ko + P]), W.hp[P],     accB[1]);
        FDOT2(U2H(WC1[ko + P]), W.hp[P],     accC[1]);
        FDOT2(U2H(WD1[ko + P]), W.hp[P],     accD[1]);
        FDOT2(U2H(WA[ko + P]),  W.hp[P + 1], accA[2]);
        FDOT2(U2H(WB[ko + P]),  W.hp[P + 1], accB[2]);
        FDOT2(U2H(WC[ko + P]),  W.hp[P + 1], accC[2]);
        FDOT2(U2H(WD[ko + P]),  W.hp[P + 1], accD[2]);
        FDOT2(U2H(WA1[ko + P]), W.hp[P + 1], accA[3]);
        FDOT2(U2H(WB1[ko + P]), W.hp[P + 1], accB[3]);
        FDOT2(U2H(WC1[ko + P]), W.hp[P + 1], accC[3]);
        FDOT2(U2H(WD1[ko + P]), W.hp[P + 1], accD[3]);
    }
}

static __device__ __forceinline__ void calc_series(
        const _Float16 (*sxr)[XSTR], const _Float16 (*sxi)[XSTR], int pos, float* v) {
    const int ix = pos + 2;
    float x0r = (float)sxr[0][ix], x0i = (float)sxi[0][ix];
    float x1r = (float)sxr[1][ix], x1i = (float)sxi[1][ix];
    float p0 = x0r * x0r + x0i * x0i;
    float p1 = x1r * x1r + x1i * x1i;
    v[0] = 2.f * p0 + p1;
    v[1] = 2.f * p1 + p0;
    v[2] = x0r * x1r + x0i * x1i;       // qr
    v[3] = x0i * x1r - x0r * x1i;       // qi
#pragma unroll
    for (int sg = 0; sg < 2; ++sg) {
        const int jx = ix - (sg + 1);
        float a0r = (float)sxr[0][jx], a0i = (float)sxi[0][jx];
        float a1r = (float)sxr[1][jx], a1i = (float)sxi[1][jx];
        float U0r = x0r * a0r + x0i * a0i;
        float U0i = x0i * a0r - x0r * a0i;
        float U1r = x1r * a1r + x1i * a1i;
        float U1i = x1i * a1r - x1r * a1i;
        const int ba = 4 + sg * 8;
        v[ba + 0] = 2.f * U0r + U1r;
        v[ba + 1] = 2.f * U1r + U0r;
        v[ba + 2] = 2.f * U0i + U1i;
        v[ba + 3] = 2.f * U1i + U0i;
        v[ba + 4] = x0r * a1r + x0i * a1i;  // Br0
        v[ba + 5] = x1r * a0r + x1i * a0i;  // Br1
        v[ba + 6] = x0i * a1r - x0r * a1i;  // Bi0
        v[ba + 7] = x1i * a0r - x1r * a0i;  // Bi1
    }
}

__global__ __launch_bounds__(256, 4) void snse_kernel(
    const float* __restrict__ g_xr, const float* __restrict__ g_xi,
    const float* __restrict__ g_ti, const float* __restrict__ g_c00,
    const float* __restrict__ g_wx, const float* __restrict__ g_wc,
    const uint* __restrict__ Wg,
    float* __restrict__ g_out)
{
    // series: 0 ps0, 1 ps1, 2 qr, 3 qi; sg: base=4+8sg: +0 Ar0 +1 Ar1 +2 Ai0 +3 Ai1
    //                                                    +4 Br0 +5 Br1 +6 Bi0 +7 Bi1
    __shared__ __align__(16) uint SE[NSER * SSTR];              // 28960 B
    __shared__ _Float16 s_xr_h[2][XSTR], s_xi_h[2][XSTR];       //  5760 B

    const int tid = threadIdx.x;
    const int b   = blockIdx.y;
    const int l0  = blockIdx.x * TL;

    const float tdb    = g_ti[b * 4 + 0];
    const float P      = expf(tdb * 0.23025850929940457f) * 0.5f;
    const float sP     = sqrtf(P);
    const float inv_sP = 1.0f / sP;
    const float C00    = g_c00[0];

    for (int idx = tid; idx < 2 * NPX; idx += 256) {
        int pidx = idx >> 1, ch = idx & 1;
        int m = l0 - 2 + pidx;
        int mw = m < 0 ? m + M_LEN : (m >= M_LEN ? m - M_LEN : m);
        int gg = (b * M_LEN + mw) * 2 + ch;
        s_xr_h[ch][pidx] = (_Float16)(g_xr[gg] * sP);
        s_xi_h[ch][pidx] = (_Float16)(g_xi[gg] * sP);
    }
    __syncthreads();

    // stage packed f16 series pairs; zero-fill beyond NPS (NaN guard)
    for (int p = tid; p < PAIRS; p += 256) {
        float v0[NSER], v1[NSER];
#pragma unroll
        for (int a = 0; a < NSER; ++a) { v0[a] = 0.f; v1[a] = 0.f; }
        const int m0 = 2 * p, m1 = 2 * p + 1;
        if (m0 < NPS) calc_series(s_xr_h, s_xi_h, m0, v0);
        if (m1 < NPS) calc_series(s_xr_h, s_xi_h, m1, v1);
#pragma unroll
        for (int a = 0; a < NSER; ++a)
            SE[a * SSTR + p] = H2U(__builtin_amdgcn_cvt_pkrtz(v0[a], v1[a]));
    }
    __syncthreads();

    const int g  = tid & 127;
    const int nn = tid >> 7;
    const int r  = g << 2;
    const int pb = g << 1;

    float acc_ix[4] = {}, acc_qr[4] = {}, acc_qi[4] = {};
    float fAr[4][4] = {}, fAi[4][4] = {}, fBr[4][4] = {}, fBi[4][4] = {};

    const uint* bps = &SE[nn * SSTR + pb];
    const uint* bqr = &SE[2 * SSTR + pb];
    const uint* bqi = &SE[3 * SSTR + pb];
    const uint *bAr[2], *bAi[2], *bBor[2], *bBoi[2], *bBxr[2], *bBxi[2];
#pragma unroll
    for (int sg = 0; sg < 2; ++sg) {
        const int ba = 4 + sg * 8;
        bAr[sg]  = &SE[(ba + 0 + nn) * SSTR + pb];
        bAi[sg]  = &SE[(ba + 2 + nn) * SSTR + pb];
        bBor[sg] = &SE[(ba + 4 + nn) * SSTR + pb];
        bBoi[sg] = &SE[(ba + 6 + nn) * SSTR + pb];
        bBxr[sg] = &SE[(ba + 4 + (1 - nn)) * SSTR + pb];
        bBxi[sg] = &SE[(ba + 6 + (1 - nn)) * SSTR + pb];
    }

    // monolithic k-loop: all 15 windows per iteration, fresh ds_reads (no
    // carried windows), guard-free pre-baked weights. sg unrolled so all
    // accumulator indices are compile-time (R7 lesson: else scratch spill).
#pragma unroll 1
    for (int k = 0; k < 13; ++k) {
        const int ko = 8 * k;
        { Win10 w = readwin(bps, ko); dot1(w, Wg + 0 * WPP, ko, acc_ix); }
        { Win10 w = readwin(bqr, ko); dot1(w, Wg + 2 * WPP, ko, acc_qr); }
        { Win10 w = readwin(bqi, ko); dot1(w, Wg + 2 * WPP, ko, acc_qi); }
#pragma unroll
        for (int sg = 0; sg < 2; ++sg) {
            const int sip = 2 + sg, sin_ = 1 - sg;
            const uint* G = Wg + (4 + sg * 12) * WPP;
            // G offsets: +0 wPr, +2 wPi, +4 wNr, +6 wNi, +8 nWpi, +10 nWnr
            {
                Win10 w = readwin(bAr[sg], ko);
                dot4w(w, G + 0 * WPP, G + 2 * WPP, G + 4 * WPP, G + 6 * WPP, ko,
                      fAr[sip], fAi[sip], fAr[sin_], fAi[sin_]);
            }
            {
                Win10 w = readwin(bAi[sg], ko);
                dot4w(w, G + 8 * WPP, G + 0 * WPP, G + 6 * WPP, G + 10 * WPP, ko,
                      fAr[sip], fAi[sip], fAr[sin_], fAi[sin_]);
            }
            {
                Win10 w = readwin(bBor[sg], ko);
                dot2w(w, G + 0 * WPP, G + 2 * WPP, ko, fBr[sip], fBi[sip]);
            }
            {
                Win10 w = readwin(bBoi[sg], ko);
                dot2w(w, G + 8 * WPP, G + 0 * WPP, ko, fBr[sip], fBi[sip]);
            }
            {
                Win10 w = readwin(bBxr[sg], ko);
                dot2w(w, G + 4 * WPP, G + 6 * WPP, ko, fBr[sin_], fBi[sin_]);
            }
            {
                Win10 w = readwin(bBxi[sg], ko);
                dot2w(w, G + 6 * WPP, G + 10 * WPP, ko, fBr[sin_], fBi[sin_]);
            }
        }
    }

    // zero-center-tap correction (zcv only); f16-rounded weights to match conv
    {
        const float wx100 = (float)(_Float16)g_wx[T_HALF];
        const float wc100 = (float)(_Float16)g_wc[T_HALF];
#pragma unroll
        for (int o = 0; o < 4; ++o) {
            const int pos = r + o + T_HALF;
            const int pp = pos >> 1, pe = pos & 1;
            h2 vps = U2H(SE[nn * SSTR + pp]);
            h2 vqr = U2H(SE[2 * SSTR + pp]);
            h2 vqi = U2H(SE[3 * SSTR + pp]);
            acc_ix[o] = fmaf(-wx100, (float)vps[pe], acc_ix[o]);
            acc_qr[o] = fmaf(-wc100, (float)vqr[pe], acc_qr[o]);
            acc_qi[o] = fmaf(-wc100, (float)vqi[pe], acc_qi[o]);
        }
    }

    // epilogue
    const int ssf[4] = {-2, -1, 1, 2};
#pragma unroll
    for (int o = 0; o < 4; ++o) {
        const int lrel = r + o;
        const int l = l0 + lrel;
        const int xc = lrel + T_HALF + 2;
        float X0r = (float)s_xr_h[0][xc], X0i = (float)s_xi_h[0][xc];
        float X1r = (float)s_xr_h[1][xc], X1i = (float)s_xi_h[1][xc];
        float pw  = X0r * X0r + X0i * X0i + X1r * X1r + X1i * X1i;
        float phi = C00 * pw + 2.f * acc_ix[o];
        float sph, cph;
        __sincosf(phi, &sph, &cph);
        float qcr = acc_qr[o];
        float qci = nn ? -acc_qi[o] : acc_qi[o];
        float br_ = nn ? X1r : X0r, bi_ = nn ? X1i : X0i;
        float or_ = nn ? X0r : X1r, oi_ = nn ? X0i : X1i;
        float ici_r = -(or_ * qci + oi_ * qcr);
        float ici_i =   or_ * qcr - oi_ * qci;
        float fw_r = 0.f, fw_i = 0.f;
#pragma unroll
        for (int si = 0; si < 4; ++si) {
            int sx = xc - ssf[si];
            float xnr  = (float)s_xr_h[nn][sx],     xni = (float)s_xi_h[nn][sx];
            float xor_ = (float)s_xr_h[1 - nn][sx], xoi = (float)s_xi_h[1 - nn][sx];
            fw_r += xnr * fAr[si][o] - xni * fAi[si][o]
                  + xor_ * fBr[si][o] - xoi * fBi[si][o];
            fw_i += xnr * fAi[si][o] + xni * fAr[si][o]
                  + xor_ * fBi[si][o] + xoi * fBr[si][o];
        }
        float out_r = br_ * cph - bi_ * sph + ici_r + fw_r;
        float out_i = br_ * sph + bi_ * cph + ici_i + fw_i;
        if (l < L_OUT) {
            int oidx = (((b * L_OUT) + l) * 2 + nn) * 2;
            g_out[oidx]     = out_r * inv_sP;
            g_out[oidx + 1] = out_i * inv_sP;
        }
    }
}

extern "C" void kernel_launch(void* const* d_in, const int* in_sizes, int n_in,
                              void* d_out, int out_size, void* d_ws, size_t ws_size,
                              hipStream_t stream) {
    const float* xr  = (const float*)d_in[0];
    const float* xi  = (const float*)d_in[1];
    const float* ti  = (const float*)d_in[2];
    const float* c00 = (const float*)d_in[3];
    const float* wx  = (const float*)d_in[4];
    const float* wc  = (const float*)d_in[5];
    const float* wr  = (const float*)d_in[6];
    const float* wi  = (const float*)d_in[7];
    float* out = (float*)d_out;
    uint* W = (uint*)d_ws;   // NWARR*WPP*4 = 11648 bytes

    prep_weights<<<dim3((NWARR * WPP + 255) / 256), dim3(256), 0, stream>>>(wx, wc, wr, wi, W);

    dim3 grid(NTILES, B_SZ, 1);
    dim3 block(256, 1, 1);
    snse_kernel<<<grid, block, 0, stream>>>(xr, xi, ti, c00, wx, wc, W, out);
}

// Round 10
// 229.255 us; speedup vs baseline: 2.6447x; 1.0642x over previous
//
#include <hip/hip_runtime.h>
#include <math.h>

#define M_LEN 40000
#define B_SZ 16
#define K_TAPS 201
#define T_HALF 100
#define L_OUT 39800          // M_LEN - K_TAPS + 1
#define TL 512               // outputs per block
#define NTILES 78            // ceil(L_OUT / TL)
#define NP 712               // TL + K_TAPS - 1
#define NPS 714              // NP + 2 : staged series positions
#define NPX 716              // NP + 4 : x positions
#define XSTR 720             // x f16 stride
#define PAIRS 360            // staged series pairs
#define SSTR 362             // series pair-array stride in dwords (even)
#define NSER 20
#define WPP 104              // weight pairs per array (208 taps)
#define NWARR 28             // 4 base + 2 sg x 12

typedef unsigned int uint;
typedef __fp16 h2 __attribute__((ext_vector_type(2)));

static __device__ __forceinline__ h2 U2H(uint u){ h2 r; __builtin_memcpy(&r,&u,4); return r; }
static __device__ __forceinline__ uint H2U(h2 h){ uint r; __builtin_memcpy(&r,&h,4); return r; }

#define FDOT2(w,v,acc) (acc) = __builtin_amdgcn_fdot2((w),(v),(acc),false)
#define PKFMA(w,v,acc) (acc) = __builtin_elementwise_fma((w),(v),(acc))

// ---------------- prep kernel -------------------------------------------------
// Weight arrays (WPP uints each): 0 wx_v0, 1 wx_v1, 2 wc_v0, 3 wc_v1,
// then per sg block at 4+sg*12: kind pairs (v0,v1) for
// kind 0 wPr, 1 wPi, 2 wNr, 3 wNi, 4 nWpi(=-wPi), 5 nWnr(=-wNr)
// version 0: pair p = (w[2p], w[2p+1]); version 1: (w[2p-1], w[2p])
static __device__ float wkind(int kind, int sg, int t,
                              const float* wr, const float* wi) {
    if (kind == 0) return (t >= 0 && t <= 200) ? wr[(2 + sg) * K_TAPS + t] : 0.f;
    if (kind == 1) return (t >= 0 && t <= 200) ? wi[(2 + sg) * K_TAPS + t] : 0.f;
    int tt = t - (sg + 1);
    if (kind == 2) return (tt >= 0 && tt <= 200) ? wr[(1 - sg) * K_TAPS + tt] : 0.f;
    if (kind == 3) return (tt >= 0 && tt <= 200) ? wi[(1 - sg) * K_TAPS + tt] : 0.f;
    if (kind == 4) return -wkind(1, sg, t, wr, wi);
    return -wkind(2, sg, t, wr, wi);
}

__global__ void prep_weights(const float* __restrict__ wx, const float* __restrict__ wc,
                             const float* __restrict__ wr, const float* __restrict__ wi,
                             uint* __restrict__ W) {
    int idx = blockIdx.x * 256 + threadIdx.x;
    if (idx >= NWARR * WPP) return;
    int p = idx % WPP;
    int a = idx / WPP;
    float f0, f1;
    if (a < 4) {
        int ver = a & 1;
        const float* src = (a < 2) ? wx : wc;
        int t0 = 2 * p - ver;
        f0 = (t0     >= 0 && t0     <= 200) ? src[t0]     : 0.f;
        f1 = (t0 + 1 >= 0 && t0 + 1 <= 200) ? src[t0 + 1] : 0.f;
    } else {
        int q = a - 4;
        int sg = q / 12, r = q % 12;
        int kind = r >> 1, ver = r & 1;
        int t0 = 2 * p - ver;
        f0 = wkind(kind, sg, t0,     wr, wi);
        f1 = wkind(kind, sg, t0 + 1, wr, wi);
    }
    W[idx] = H2U(__builtin_amdgcn_cvt_pkrtz(f0, f1));
}

// ---------------- window + dot helpers ----------------------------------------
struct Win10 { h2 hp[10]; };

static __device__ __forceinline__ Win10 readwin(const uint* base, int ko) {
    Win10 w;
    uint2 u0 = *(const uint2*)(base + ko);
    uint2 u1 = *(const uint2*)(base + ko + 2);
    uint2 u2 = *(const uint2*)(base + ko + 4);
    uint2 u3 = *(const uint2*)(base + ko + 6);
    uint2 u4 = *(const uint2*)(base + ko + 8);
    w.hp[0] = U2H(u0.x); w.hp[1] = U2H(u0.y);
    w.hp[2] = U2H(u1.x); w.hp[3] = U2H(u1.y);
    w.hp[4] = U2H(u2.x); w.hp[5] = U2H(u2.y);
    w.hp[6] = U2H(u3.x); w.hp[7] = U2H(u3.y);
    w.hp[8] = U2H(u4.x); w.hp[9] = U2H(u4.y);
    return w;
}

// f32 fdot2 path (precision-critical ps/q convs). 32 fdot2.
static __device__ __forceinline__ void dot1(const Win10& W, const uint* __restrict__ W0,
                                            int ko, float* acc) {
    const uint* W1 = W0 + WPP;
#pragma unroll
    for (int P = 0; P < 8; ++P) {
        FDOT2(U2H(W0[ko + P]), W.hp[P],     acc[0]);
        FDOT2(U2H(W1[ko + P]), W.hp[P],     acc[1]);
        FDOT2(U2H(W0[ko + P]), W.hp[P + 1], acc[2]);
        FDOT2(U2H(W1[ko + P]), W.hp[P + 1], acc[3]);
    }
}

// pk_fma_f16 path: 2 weight vectors -> 2 h2 acc groups. 64 pk_fma.
static __device__ __forceinline__ void dot2w(const Win10& W,
                                             const uint* __restrict__ WA,
                                             const uint* __restrict__ WB,
                                             int ko, h2* accA, h2* accB) {
    const uint* WA1 = WA + WPP; const uint* WB1 = WB + WPP;
#pragma unroll
    for (int P = 0; P < 8; ++P) {
        PKFMA(U2H(WA[ko + P]),  W.hp[P],     accA[0]);
        PKFMA(U2H(WA1[ko + P]), W.hp[P],     accA[1]);
        PKFMA(U2H(WA[ko + P]),  W.hp[P + 1], accA[2]);
        PKFMA(U2H(WA1[ko + P]), W.hp[P + 1], accA[3]);
        PKFMA(U2H(WB[ko + P]),  W.hp[P],     accB[0]);
        PKFMA(U2H(WB1[ko + P]), W.hp[P],     accB[1]);
        PKFMA(U2H(WB[ko + P]),  W.hp[P + 1], accB[2]);
        PKFMA(U2H(WB1[ko + P]), W.hp[P + 1], accB[3]);
    }
}

// pk_fma_f16 path: 4 weight vectors -> 4 h2 acc groups. 128 pk_fma.
static __device__ __forceinline__ void dot4w(const Win10& W,
                                             const uint* __restrict__ WA,
                                             const uint* __restrict__ WB,
                                             const uint* __restrict__ WC,
                                             const uint* __restrict__ WD,
                                             int ko, h2* accA, h2* accB,
                                             h2* accC, h2* accD) {
    const uint* WA1 = WA + WPP; const uint* WB1 = WB + WPP;
    const uint* WC1 = WC + WPP; const uint* WD1 = WD + WPP;
#pragma unroll
    for (int P = 0; P < 8; ++P) {
        PKFMA(U2H(WA[ko + P]),  W.hp[P],     accA[0]);
        PKFMA(U2H(WB[ko + P]),  W.hp[P],     accB[0]);
        PKFMA(U2H(WC[ko + P]),  W.hp[P],     accC[0]);
        PKFMA(U2H(WD[ko + P]),  W.hp[P],     accD[0]);
        PKFMA(U2H(WA1[ko + P]), W.hp[P],     accA[1]);
        PKFMA(U2H(WB1[ko + P]), W.hp[P],     accB[1]);
        PKFMA(U2H(WC1[ko + P]), W.hp[P],     accC[1]);
        PKFMA(U2H(WD1[ko + P]), W.hp[P],     accD[1]);
        PKFMA(U2H(WA[ko + P]),  W.hp[P + 1], accA[2]);
        PKFMA(U2H(WB[ko + P]),  W.hp[P + 1], accB[2]);
        PKFMA(U2H(WC[ko + P]),  W.hp[P + 1], accC[2]);
        PKFMA(U2H(WD[ko + P]),  W.hp[P + 1], accD[2]);
        PKFMA(U2H(WA1[ko + P]), W.hp[P + 1], accA[3]);
        PKFMA(U2H(WB1[ko + P]), W.hp[P + 1], accB[3]);
        PKFMA(U2H(WC1[ko + P]), W.hp[P + 1], accC[3]);
        PKFMA(U2H(WD1[ko + P]), W.hp[P + 1], accD[3]);
    }
}

static __device__ __forceinline__ void calc_series(
        const _Float16 (*sxr)[XSTR], const _Float16 (*sxi)[XSTR], int pos, float* v) {
    const int ix = pos + 2;
    float x0r = (float)sxr[0][ix], x0i = (float)sxi[0][ix];
    float x1r = (float)sxr[1][ix], x1i = (float)sxi[1][ix];
    float p0 = x0r * x0r + x0i * x0i;
    float p1 = x1r * x1r + x1i * x1i;
    v[0] = 2.f * p0 + p1;
    v[1] = 2.f * p1 + p0;
    v[2] = x0r * x1r + x0i * x1i;       // qr
    v[3] = x0i * x1r - x0r * x1i;       // qi
#pragma unroll
    for (int sg = 0; sg < 2; ++sg) {
        const int jx = ix - (sg + 1);
        float a0r = (float)sxr[0][jx], a0i = (float)sxi[0][jx];
        float a1r = (float)sxr[1][jx], a1i = (float)sxi[1][jx];
        float U0r = x0r * a0r + x0i * a0i;
        float U0i = x0i * a0r - x0r * a0i;
        float U1r = x1r * a1r + x1i * a1i;
        float U1i = x1i * a1r - x1r * a1i;
        const int ba = 4 + sg * 8;
        v[ba + 0] = 2.f * U0r + U1r;
        v[ba + 1] = 2.f * U1r + U0r;
        v[ba + 2] = 2.f * U0i + U1i;
        v[ba + 3] = 2.f * U1i + U0i;
        v[ba + 4] = x0r * a1r + x0i * a1i;  // Br0
        v[ba + 5] = x1r * a0r + x1i * a0i;  // Br1
        v[ba + 6] = x0i * a1r - x0r * a1i;  // Bi0
        v[ba + 7] = x1i * a0r - x1r * a0i;  // Bi1
    }
}

__global__ __launch_bounds__(256, 4) void snse_kernel(
    const float* __restrict__ g_xr, const float* __restrict__ g_xi,
    const float* __restrict__ g_ti, const float* __restrict__ g_c00,
    const float* __restrict__ g_wx, const float* __restrict__ g_wc,
    const uint* __restrict__ Wg,
    float* __restrict__ g_out)
{
    __shared__ __align__(16) uint SE[NSER * SSTR];              // 28960 B
    __shared__ _Float16 s_xr_h[2][XSTR], s_xi_h[2][XSTR];       //  5760 B

    const int tid = threadIdx.x;
    const int b   = blockIdx.y;
    const int l0  = blockIdx.x * TL;

    const float tdb    = g_ti[b * 4 + 0];
    const float P      = expf(tdb * 0.23025850929940457f) * 0.5f;
    const float sP     = sqrtf(P);
    const float inv_sP = 1.0f / sP;
    const float C00    = g_c00[0];

    for (int idx = tid; idx < 2 * NPX; idx += 256) {
        int pidx = idx >> 1, ch = idx & 1;
        int m = l0 - 2 + pidx;
        int mw = m < 0 ? m + M_LEN : (m >= M_LEN ? m - M_LEN : m);
        int gg = (b * M_LEN + mw) * 2 + ch;
        s_xr_h[ch][pidx] = (_Float16)(g_xr[gg] * sP);
        s_xi_h[ch][pidx] = (_Float16)(g_xi[gg] * sP);
    }
    __syncthreads();

    // stage packed f16 series pairs; zero-fill beyond NPS (NaN guard)
    for (int p = tid; p < PAIRS; p += 256) {
        float v0[NSER], v1[NSER];
#pragma unroll
        for (int a = 0; a < NSER; ++a) { v0[a] = 0.f; v1[a] = 0.f; }
        const int m0 = 2 * p, m1 = 2 * p + 1;
        if (m0 < NPS) calc_series(s_xr_h, s_xi_h, m0, v0);
        if (m1 < NPS) calc_series(s_xr_h, s_xi_h, m1, v1);
#pragma unroll
        for (int a = 0; a < NSER; ++a)
            SE[a * SSTR + p] = H2U(__builtin_amdgcn_cvt_pkrtz(v0[a], v1[a]));
    }
    __syncthreads();

    const int g  = tid & 127;
    const int nn = tid >> 7;
    const int r  = g << 2;
    const int pb = g << 1;

    float acc_ix[4] = {}, acc_qr[4] = {}, acc_qi[4] = {};
    h2 hAr[4][4] = {}, hAi[4][4] = {}, hBr[4][4] = {}, hBi[4][4] = {};

    const uint* bps = &SE[nn * SSTR + pb];
    const uint* bqr = &SE[2 * SSTR + pb];
    const uint* bqi = &SE[3 * SSTR + pb];
    const uint *bAr[2], *bAi[2], *bBor[2], *bBoi[2], *bBxr[2], *bBxi[2];
#pragma unroll
    for (int sg = 0; sg < 2; ++sg) {
        const int ba = 4 + sg * 8;
        bAr[sg]  = &SE[(ba + 0 + nn) * SSTR + pb];
        bAi[sg]  = &SE[(ba + 2 + nn) * SSTR + pb];
        bBor[sg] = &SE[(ba + 4 + nn) * SSTR + pb];
        bBoi[sg] = &SE[(ba + 6 + nn) * SSTR + pb];
        bBxr[sg] = &SE[(ba + 4 + (1 - nn)) * SSTR + pb];
        bBxi[sg] = &SE[(ba + 6 + (1 - nn)) * SSTR + pb];
    }

    // monolithic k-loop; sg unrolled (R7 lesson: runtime acc indices -> scratch)
#pragma unroll 1
    for (int k = 0; k < 13; ++k) {
        const int ko = 8 * k;
        { Win10 w = readwin(bps, ko); dot1(w, Wg + 0 * WPP, ko, acc_ix); }
        { Win10 w = readwin(bqr, ko); dot1(w, Wg + 2 * WPP, ko, acc_qr); }
        { Win10 w = readwin(bqi, ko); dot1(w, Wg + 2 * WPP, ko, acc_qi); }
#pragma unroll
        for (int sg = 0; sg < 2; ++sg) {
            const int sip = 2 + sg, sin_ = 1 - sg;
            const uint* G = Wg + (4 + sg * 12) * WPP;
            // G offsets: +0 wPr, +2 wPi, +4 wNr, +6 wNi, +8 nWpi, +10 nWnr
            {
                Win10 w = readwin(bAr[sg], ko);
                dot4w(w, G + 0 * WPP, G + 2 * WPP, G + 4 * WPP, G + 6 * WPP, ko,
                      hAr[sip], hAi[sip], hAr[sin_], hAi[sin_]);
            }
            {
                Win10 w = readwin(bAi[sg], ko);
                dot4w(w, G + 8 * WPP, G + 0 * WPP, G + 6 * WPP, G + 10 * WPP, ko,
                      hAr[sip], hAi[sip], hAr[sin_], hAi[sin_]);
            }
            {
                Win10 w = readwin(bBor[sg], ko);
                dot2w(w, G + 0 * WPP, G + 2 * WPP, ko, hBr[sip], hBi[sip]);
            }
            {
                Win10 w = readwin(bBoi[sg], ko);
                dot2w(w, G + 8 * WPP, G + 0 * WPP, ko, hBr[sip], hBi[sip]);
            }
            {
                Win10 w = readwin(bBxr[sg], ko);
                dot2w(w, G + 4 * WPP, G + 6 * WPP, ko, hBr[sin_], hBi[sin_]);
            }
            {
                Win10 w = readwin(bBxi[sg], ko);
                dot2w(w, G + 6 * WPP, G + 10 * WPP, ko, hBr[sin_], hBi[sin_]);
            }
        }
    }

    // combine packed f16 sub-accumulators -> f32
    float fAr[4][4], fAi[4][4], fBr[4][4], fBi[4][4];
#pragma unroll
    for (int si = 0; si < 4; ++si)
#pragma unroll
        for (int o = 0; o < 4; ++o) {
            fAr[si][o] = (float)hAr[si][o].x + (float)hAr[si][o].y;
            fAi[si][o] = (float)hAi[si][o].x + (float)hAi[si][o].y;
            fBr[si][o] = (float)hBr[si][o].x + (float)hBr[si][o].y;
            fBi[si][o] = (float)hBi[si][o].x + (float)hBi[si][o].y;
        }

    // zero-center-tap correction (zcv only); f16-rounded weights to match conv
    {
        const float wx100 = (float)(_Float16)g_wx[T_HALF];
        const float wc100 = (float)(_Float16)g_wc[T_HALF];
#pragma unroll
        for (int o = 0; o < 4; ++o) {
            const int pos = r + o + T_HALF;
            const int pp = pos >> 1, pe = pos & 1;
            h2 vps = U2H(SE[nn * SSTR + pp]);
            h2 vqr = U2H(SE[2 * SSTR + pp]);
            h2 vqi = U2H(SE[3 * SSTR + pp]);
            acc_ix[o] = fmaf(-wx100, (float)vps[pe], acc_ix[o]);
            acc_qr[o] = fmaf(-wc100, (float)vqr[pe], acc_qr[o]);
            acc_qi[o] = fmaf(-wc100, (float)vqi[pe], acc_qi[o]);
        }
    }

    // epilogue
    const int ssf[4] = {-2, -1, 1, 2};
#pragma unroll
    for (int o = 0; o < 4; ++o) {
        const int lrel = r + o;
        const int l = l0 + lrel;
        const int xc = lrel + T_HALF + 2;
        float X0r = (float)s_xr_h[0][xc], X0i = (float)s_xi_h[0][xc];
        float X1r = (float)s_xr_h[1][xc], X1i = (float)s_xi_h[1][xc];
        float pw  = X0r * X0r + X0i * X0i + X1r * X1r + X1i * X1i;
        float phi = C00 * pw + 2.f * acc_ix[o];
        float sph, cph;
        __sincosf(phi, &sph, &cph);
        float qcr = acc_qr[o];
        float qci = nn ? -acc_qi[o] : acc_qi[o];
        float br_ = nn ? X1r : X0r, bi_ = nn ? X1i : X0i;
        float or_ = nn ? X0r : X1r, oi_ = nn ? X0i : X1i;
        float ici_r = -(or_ * qci + oi_ * qcr);
        float ici_i =   or_ * qcr - oi_ * qci;
        float fw_r = 0.f, fw_i = 0.f;
#pragma unroll
        for (int si = 0; si < 4; ++si) {
            int sx = xc - ssf[si];
            float xnr  = (float)s_xr_h[nn][sx],     xni = (float)s_xi_h[nn][sx];
            float xor_ = (float)s_xr_h[1 - nn][sx], xoi = (float)s_xi_h[1 - nn][sx];
            fw_r += xnr * fAr[si][o] - xni * fAi[si][o]
                  + xor_ * fBr[si][o] - xoi * fBi[si][o];
            fw_i += xnr * fAi[si][o] + xni * fAr[si][o]
                  + xor_ * fBi[si][o] + xoi * fBr[si][o];
        }
        float out_r = br_ * cph - bi_ * sph + ici_r + fw_r;
        float out_i = br_ * sph + bi_ * cph + ici_i + fw_i;
        if (l < L_OUT) {
            int oidx = (((b * L_OUT) + l) * 2 + nn) * 2;
            g_out[oidx]     = out_r * inv_sP;
            g_out[oidx + 1] = out_i * inv_sP;
        }
    }
}

extern "C" void kernel_launch(void* const* d_in, const int* in_sizes, int n_in,
                              void* d_out, int out_size, void* d_ws, size_t ws_size,
                              hipStream_t stream) {
    const float* xr  = (const float*)d_in[0];
    const float* xi  = (const float*)d_in[1];
    const float* ti  = (const float*)d_in[2];
    const float* c00 = (const float*)d_in[3];
    const float* wx  = (const float*)d_in[4];
    const float* wc  = (const float*)d_in[5];
    const float* wr  = (const float*)d_in[6];
    const float* wi  = (const float*)d_in[7];
    float* out = (float*)d_out;
    uint* W = (uint*)d_ws;   // NWARR*WPP*4 = 11648 bytes

    prep_weights<<<dim3((NWARR * WPP + 255) / 256), dim3(256), 0, stream>>>(wx, wc, wr, wi, W);

    dim3 grid(NTILES, B_SZ, 1);
    dim3 block(256, 1, 1);
    snse_kernel<<<grid, block, 0, stream>>>(xr, xi, ti, c00, wx, wc, W, out);
}